// Round 1
// baseline (1827.894 us; speedup 1.0000x reference)
//
#include <hip/hip_runtime.h>

// ---------------------------------------------------------------------------
// AppUsageFEDformer forward on MI355X (gfx950).
// Pipeline: embed -> 2x [Wq gemm -> DFT(32 modes) -> complex mix -> iDFT ->
//           Wo gemm (+res) -> decomp -> conv1(relu) -> conv2(+res) -> decomp]
//           -> layernorm(+L-mean sub) -> last-token concat -> proj gemm.
// GEMMs: bf16 MFMA 16x16x32, 128x128x32 tiles, global_load_lds(16B) staging.
// Everything else fp32.  Reference reshape quirk: fourier out (B,H,E,L) is
// RESHAPED to (B,L,H*E) => inverse writes out[b][h*64+o][l].
// ---------------------------------------------------------------------------

typedef unsigned short u16;
typedef float f32x4 __attribute__((ext_vector_type(4)));
typedef __bf16 bf16x8 __attribute__((ext_vector_type(8)));

__device__ __forceinline__ u16 f2b(float f) {
  unsigned u = __float_as_uint(f);
  return (u16)((u + 0x7FFFu + ((u >> 16) & 1u)) >> 16);
}

__device__ __forceinline__ void async16(const void* g, void* l) {
  __builtin_amdgcn_global_load_lds(
      (const __attribute__((address_space(1))) void*)g,
      (__attribute__((address_space(3))) void*)l, 16, 0, 0);
}

// ---------------- bf16 MFMA GEMM:  C = A(MxK) * B(NxK)^T (+bias)(+res)(relu)
template<bool BIAS, bool RELU, bool RES, bool OUTBF16, bool GUARD>
__global__ __launch_bounds__(256, 2)
void k_gemm(const u16* __restrict__ A, const u16* __restrict__ B,
            const float* __restrict__ bias, const float* __restrict__ res,
            float* __restrict__ Cf, u16* __restrict__ Cb,
            int M, int N, int K)
{
  __shared__ __align__(16) u16 sA[128 * 32];
  __shared__ __align__(16) u16 sB[128 * 32];
  const int tid = threadIdx.x;
  const int wave = tid >> 6, lane = tid & 63;
  const int bn = blockIdx.x, bm = blockIdx.y;
  const int wm = (wave >> 1) * 64, wn = (wave & 1) * 64;

  // staging geometry: 8 chunks of 1KB per 8KB tile; wave w owns chunks 2w,2w+1
  const int c0 = wave * 2, c1 = wave * 2 + 1;
  const int off0 = c0 * 1024 + lane * 16, off1 = c1 * 1024 + lane * 16;
  const int ra0 = off0 >> 6, ca0 = off0 & 63;   // row (64B per row of 32 bf16)
  const int ra1 = off1 >> 6, ca1 = off1 & 63;
  int gma0 = bm * 128 + ra0, gma1 = bm * 128 + ra1;
  int gnb0 = bn * 128 + ra0, gnb1 = bn * 128 + ra1;
  if (GUARD) {
    gma0 = gma0 < M ? gma0 : M - 1;
    gma1 = gma1 < M ? gma1 : M - 1;
    gnb0 = gnb0 < N ? gnb0 : N - 1;
    gnb1 = gnb1 < N ? gnb1 : N - 1;
  }
  const size_t rb = (size_t)K * 2;
  const char* pa0 = (const char*)A + (size_t)gma0 * rb + ca0;
  const char* pa1 = (const char*)A + (size_t)gma1 * rb + ca1;
  const char* pb0 = (const char*)B + (size_t)gnb0 * rb + ca0;
  const char* pb1 = (const char*)B + (size_t)gnb1 * rb + ca1;
  void* la0 = (void*)&sA[c0 * 512];
  void* la1 = (void*)&sA[c1 * 512];
  void* lb0 = (void*)&sB[c0 * 512];
  void* lb1 = (void*)&sB[c1 * 512];

  f32x4 acc[4][4];
  const f32x4 z = {0.f, 0.f, 0.f, 0.f};
#pragma unroll
  for (int i = 0; i < 4; ++i)
#pragma unroll
    for (int j = 0; j < 4; ++j) acc[i][j] = z;

  const int r = lane & 15, qd = lane >> 4;
  const int nk = K >> 5;
  for (int kt = 0; kt < nk; ++kt) {
    const size_t ko = (size_t)kt * 64;
    async16(pa0 + ko, la0);
    async16(pa1 + ko, la1);
    async16(pb0 + ko, lb0);
    async16(pb1 + ko, lb1);
    __syncthreads();   // drains vmcnt -> staged data visible
    bf16x8 af[4], bg[4];
#pragma unroll
    for (int mi = 0; mi < 4; ++mi)
      af[mi] = *(const bf16x8*)&sA[(wm + mi * 16 + r) * 32 + qd * 8];
#pragma unroll
    for (int ni = 0; ni < 4; ++ni)
      bg[ni] = *(const bf16x8*)&sB[(wn + ni * 16 + r) * 32 + qd * 8];
#pragma unroll
    for (int mi = 0; mi < 4; ++mi)
#pragma unroll
      for (int ni = 0; ni < 4; ++ni)
        acc[mi][ni] = __builtin_amdgcn_mfma_f32_16x16x32_bf16(
            af[mi], bg[ni], acc[mi][ni], 0, 0, 0);
    __syncthreads();   // all waves done reading LDS before next stage
  }

#pragma unroll
  for (int mi = 0; mi < 4; ++mi) {
#pragma unroll
    for (int ni = 0; ni < 4; ++ni) {
#pragma unroll
      for (int e = 0; e < 4; ++e) {
        int gm = bm * 128 + wm + mi * 16 + qd * 4 + e;  // C/D: row=quad*4+reg
        int gn = bn * 128 + wn + ni * 16 + r;           //       col=lane&15
        if (GUARD && (gm >= M || gn >= N)) continue;
        float v = acc[mi][ni][e];
        if (BIAS) v += bias[gn];
        if (RES)  v += res[(size_t)gm * N + gn];
        if (RELU) v = v > 0.f ? v : 0.f;
        if (OUTBF16) Cb[(size_t)gm * N + gn] = f2b(v);
        else         Cf[(size_t)gm * N + gn] = v;
      }
    }
  }
}

// ---------------- misc small kernels ----------------
__global__ void k_basis(float* __restrict__ cosT, float* __restrict__ sinT,
                        float* __restrict__ cosTT, float* __restrict__ sinTT)
{
  int id = blockIdx.x * 256 + threadIdx.x;  // 512*32
  if (id >= 16384) return;
  int l = id >> 5, m = id & 31;
  int ph = (l * m) & 511;
  float ang = (float)ph * (6.283185307179586f / 512.f);
  float s, c;
  __sincosf(ang, &s, &c);
  cosT[l * 32 + m] = c;  sinT[l * 32 + m] = s;     // [l][m] for DFT staging
  cosTT[m * 512 + l] = c; sinTT[m * 512 + l] = s;  // [m][l] for inverse
}

__global__ void k_convert(const float* __restrict__ in, u16* __restrict__ out, int n)
{
  int id = blockIdx.x * 256 + threadIdx.x;
  if (id < n) out[id] = f2b(in[id]);
}

__global__ void k_convproj(const float* __restrict__ w, u16* __restrict__ o)
{
  int id = blockIdx.x * 256 + threadIdx.x;  // 10000*544
  if (id >= 10000 * 544) return;
  int n = id / 544, k = id % 544;
  o[id] = f2b(k < 536 ? w[(size_t)n * 536 + k] : 0.f);
}

__global__ void k_embed(const int* __restrict__ xapp, const float* __restrict__ xtime,
                        const float* __restrict__ emb, const float* __restrict__ tw,
                        const float* __restrict__ tb, float* __restrict__ xf,
                        u16* __restrict__ xb)
{
  int id = blockIdx.x * 256 + threadIdx.x;  // B*L*D = 16.7M
  int d = id & 511, bl = id >> 9;
  float v = emb[(size_t)xapp[bl] * 512 + d] + xtime[bl] * tw[d] + tb[d];
  xf[id] = v;
  xb[id] = f2b(v);
}

// DFT: spec[b][m][d]    = sum_l q[b,l,d] cos(2pi m l/512)   (m<32)
//      spec[b][32+m][d] = -sum_l q[b,l,d] sin(2pi m l/512)
__global__ __launch_bounds__(512)
void k_dft(const float* __restrict__ q, const float* __restrict__ cosT,
           const float* __restrict__ sinT, float* __restrict__ spec)
{
  __shared__ float bc[512][8];
  __shared__ float bs[512][8];
  int b = blockIdx.x, mg = blockIdx.y, t = threadIdx.x;
  for (int i = t; i < 4096; i += 512) {
    int l = i >> 3, mm = i & 7;
    bc[l][mm] = cosT[l * 32 + mg * 8 + mm];
    bs[l][mm] = sinT[l * 32 + mg * 8 + mm];
  }
  __syncthreads();
  float aR[8] = {}, aI[8] = {};
  const float* qb = q + (size_t)b * 262144;
#pragma unroll 4
  for (int l = 0; l < 512; ++l) {
    float v = qb[l * 512 + t];
#pragma unroll
    for (int mm = 0; mm < 8; ++mm) {
      aR[mm] = fmaf(v, bc[l][mm], aR[mm]);
      aI[mm] = fmaf(-v, bs[l][mm], aI[mm]);
    }
  }
  float* sp = spec + (size_t)b * 32768;
#pragma unroll
  for (int mm = 0; mm < 8; ++mm) {
    int m = mg * 8 + mm;
    sp[m * 512 + t] = aR[mm];
    sp[(32 + m) * 512 + t] = aI[mm];
  }
}

// mode mix: out[b,h,o,m] = sum_i xs[b,h,i,m] * (wr+j wi)[h,i,o,m]
__global__ void k_mix(const float* __restrict__ spec, const float* __restrict__ wr,
                      const float* __restrict__ wi, float* __restrict__ spec2)
{
  __shared__ float swr[64][64], swi[64][64];   // [i][o]
  __shared__ float sre[4][64], sim[4][64];     // [bsub][i]
  int h = blockIdx.x >> 5, m = blockIdx.x & 31, t = threadIdx.x;
  for (int i = t; i < 4096; i += 256) {
    int ii = i >> 6, oo = i & 63;
    size_t idx = ((size_t)((h * 64 + ii) * 64 + oo)) * 32 + m;
    swr[ii][oo] = wr[idx];
    swi[ii][oo] = wi[idx];
  }
  int o = t & 63, bsub = t >> 6;
  for (int b0 = 0; b0 < 64; b0 += 4) {
    __syncthreads();
    int b = b0 + bsub;
    const float* spb = spec + (size_t)b * 32768;
    sre[bsub][o] = spb[m * 512 + h * 64 + o];
    sim[bsub][o] = spb[(32 + m) * 512 + h * 64 + o];
    __syncthreads();
    float aR = 0.f, aI = 0.f;
#pragma unroll 8
    for (int i = 0; i < 64; ++i) {
      float xr = sre[bsub][i], xi = sim[bsub][i];
      float wrv = swr[i][o], wiv = swi[i][o];
      aR += xr * wrv - xi * wiv;
      aI += xr * wiv + xi * wrv;
    }
    float* sp2 = spec2 + (size_t)b * 32768;
    sp2[m * 512 + h * 64 + o] = aR;
    sp2[(32 + m) * 512 + h * 64 + o] = aI;
  }
}

// inverse: out[b][d][l] = (1/512)(Re0 + 2*sum_{m=1..31}(Re_m cos - Im_m sin))
// written bf16 in the reference's reshape layout (row = b*512 + d, col = l)
__global__ void k_inv(const float* __restrict__ spec2, const float* __restrict__ cosTT,
                      const float* __restrict__ sinTT, u16* __restrict__ outb)
{
  int id = blockIdx.x * 256 + threadIdx.x;  // 64*512*512
  int l = id & 511;
  int d = (id >> 9) & 511;
  int b = id >> 18;
  const float* sp = spec2 + (size_t)b * 32768 + d;
  float acc = sp[0];  // m=0: irfft drops Im of bin 0
#pragma unroll
  for (int m = 1; m < 32; ++m) {
    float re = sp[(size_t)m * 512];
    float im = sp[(size_t)(32 + m) * 512];
    acc += 2.f * (re * cosTT[m * 512 + l] - im * sinTT[m * 512 + l]);
  }
  outb[id] = f2b(acc * (1.f / 512.f));
}

// series_decomp: out = x - movavg_25(x) with edge padding; writes fp32 + bf16
__global__ void k_decomp(const float* __restrict__ in, float* __restrict__ outf,
                         u16* __restrict__ outb)
{
  int id = blockIdx.x * 256 + threadIdx.x;  // B*D*2 halves = 65536
  int d = id & 511;
  int half = (id >> 9) & 1;
  int b = id >> 10;
  const float* xb = in + (size_t)b * 262144 + d;
  int l0 = half * 256;
  float sum = 0.f;
#pragma unroll
  for (int j = -12; j <= 12; ++j) {
    int idx = l0 + j;
    idx = idx < 0 ? 0 : idx;
    sum += xb[idx * 512];
  }
#pragma unroll 4
  for (int l = l0; l < l0 + 256; ++l) {
    float xv = xb[l * 512];
    float o = xv - sum * (1.f / 25.f);
    size_t oi = ((size_t)b * 512 + l) * 512 + d;
    outf[oi] = o;
    outb[oi] = f2b(o);
    int ia = l + 13 > 511 ? 511 : l + 13;
    int ir = l - 12 < 0 ? 0 : l - 12;
    sum += xb[ia * 512] - xb[ir * 512];
  }
}

__global__ void k_lnstats(const float* __restrict__ x, float* __restrict__ mu,
                          float* __restrict__ rs)
{
  int row = blockIdx.x;
  const float* xr = x + (size_t)row * 512;
  int t = threadIdx.x;
  float v0 = xr[t], v1 = xr[t + 256];
  float s = v0 + v1, ss = v0 * v0 + v1 * v1;
#pragma unroll
  for (int off = 32; off; off >>= 1) {
    s += __shfl_down(s, off);
    ss += __shfl_down(ss, off);
  }
  __shared__ float as[4], ass[4];
  if ((t & 63) == 0) { as[t >> 6] = s; ass[t >> 6] = ss; }
  __syncthreads();
  if (t == 0) {
    float S = as[0] + as[1] + as[2] + as[3];
    float SS = ass[0] + ass[1] + ass[2] + ass[3];
    float m = S * (1.f / 512.f);
    float var = SS * (1.f / 512.f) - m * m;
    mu[row] = m;
    rs[row] = rsqrtf(var + 1e-5f);
  }
}

// head: cat[b][d] = w_d * (ln_last - mean_l(ln));  norm_b cancels.
__global__ void k_lastcat(const float* __restrict__ x, const float* __restrict__ mu,
                          const float* __restrict__ rs, const float* __restrict__ nw,
                          u16* __restrict__ cat)
{
  int id = blockIdx.x * 256 + threadIdx.x;  // B*D = 32768
  int b = id >> 9, d = id & 511;
  const float* xb = x + (size_t)b * 262144;
  const float* mub = mu + b * 512;
  const float* rsb = rs + b * 512;
  float acc = 0.f;
#pragma unroll 4
  for (int l = 0; l < 512; ++l)
    acc += (xb[l * 512 + d] - mub[l]) * rsb[l];
  float lastv = (xb[511 * 512 + d] - mub[511]) * rsb[511];
  float v = nw[d] * (lastv - acc * (1.f / 512.f));
  cat[b * 544 + d] = f2b(v);
}

__global__ void k_timecat(const float* __restrict__ tv, u16* __restrict__ cat)
{
  int id = blockIdx.x * 256 + threadIdx.x;  // 64*32
  if (id >= 2048) return;
  int b = id >> 5, j = id & 31;
  int pos = 512 + j;
  float v = (pos < 536) ? tv[((size_t)b * 512 + 511) * 24 + (pos - 512)] : 0.f;
  cat[b * 544 + pos] = f2b(v);
}

// ---------------------------------------------------------------------------
extern "C" void kernel_launch(void* const* d_in, const int* in_sizes, int n_in,
                              void* d_out, int out_size, void* d_ws, size_t ws_size,
                              hipStream_t stream)
{
  (void)in_sizes; (void)n_in; (void)out_size; (void)ws_size;
  const int*   x_app  = (const int*)  d_in[0];
  const float* x_time = (const float*)d_in[1];
  const float* tvec   = (const float*)d_in[2];
  // d_in[3] targets: unused by reference output
  const float* emb    = (const float*)d_in[4];
  const float* time_w = (const float*)d_in[5];
  const float* time_b = (const float*)d_in[6];
  const float* Wq     = (const float*)d_in[7];
  const float* bq     = (const float*)d_in[8];
  const float* Wo     = (const float*)d_in[9];
  const float* bo     = (const float*)d_in[10];
  const float* fwr    = (const float*)d_in[11];
  const float* fwi    = (const float*)d_in[12];
  const float* c1     = (const float*)d_in[13];
  const float* c2     = (const float*)d_in[14];
  const float* norm_w = (const float*)d_in[15];
  // d_in[16] norm_b: cancels in (xh - mean_l xh)
  const float* proj_w = (const float*)d_in[17];
  const float* proj_b = (const float*)d_in[18];
  float* out = (float*)d_out;

  char* w = (char*)d_ws;
  auto alloc = [&](size_t bytes) -> char* {
    char* p = w;
    w += (bytes + 255) & ~(size_t)255;
    return p;
  };
  float* Ax   = (float*)alloc(67108864);          // x fp32 (B,L,D)
  float* Bs   = (float*)alloc(67108864);          // q / t1 / t2 fp32
  u16*   Cb   = (u16*)  alloc(33554432);          // bf16 activation
  u16*   Yb   = (u16*)  alloc(33554432);          // conv1 out chunk (8192x2048)
  float* S1   = (float*)alloc(8388608);           // spec (B,64,D)
  float* S2   = (float*)alloc(8388608);           // mixed spec
  u16*   wqb  = (u16*)  alloc(2 * 262144 * 2);
  u16*   wob  = (u16*)  alloc(2 * 262144 * 2);
  u16*   c1b  = (u16*)  alloc(2 * 1048576 * 2);
  u16*   c2b  = (u16*)  alloc(2 * 1048576 * 2);
  u16*   pwb  = (u16*)  alloc(10000 * 544 * 2);
  float* cosT = (float*)alloc(65536);
  float* sinT = (float*)alloc(65536);
  float* cosTT= (float*)alloc(65536);
  float* sinTT= (float*)alloc(65536);
  float* muB  = (float*)alloc(131072);
  float* rsB  = (float*)alloc(131072);
  u16*   cat  = (u16*)  alloc(64 * 544 * 2);

  k_basis<<<64, 256, 0, stream>>>(cosT, sinT, cosTT, sinTT);
  k_convert<<<2048, 256, 0, stream>>>(Wq, wqb, 524288);
  k_convert<<<2048, 256, 0, stream>>>(Wo, wob, 524288);
  k_convert<<<8192, 256, 0, stream>>>(c1, c1b, 2097152);
  k_convert<<<8192, 256, 0, stream>>>(c2, c2b, 2097152);
  k_convproj<<<21250, 256, 0, stream>>>(proj_w, pwb);
  k_embed<<<65536, 256, 0, stream>>>(x_app, x_time, emb, time_w, time_b, Ax, Cb);

  for (int l = 0; l < 2; ++l) {
    const u16* wq_l = wqb + l * 262144;
    const u16* wo_l = wob + l * 262144;
    const u16* c1_l = c1b + l * 1048576;
    const u16* c2_l = c2b + l * 1048576;
    const float* fwr_l = fwr + (size_t)l * 1048576;
    const float* fwi_l = fwi + (size_t)l * 1048576;

    // q = x_bf16 @ Wq^T + bq
    k_gemm<true, false, false, false, false><<<dim3(4, 256), 256, 0, stream>>>(
        Cb, wq_l, bq + l * 512, nullptr, Bs, nullptr, 32768, 512, 512);
    k_dft<<<dim3(64, 4), 512, 0, stream>>>(Bs, cosT, sinT, S1);
    k_mix<<<256, 256, 0, stream>>>(S1, fwr_l, fwi_l, S2);
    k_inv<<<65536, 256, 0, stream>>>(S2, cosTT, sinTT, Cb);
    // t1 = fourier_reshaped @ Wo^T + bo + x
    k_gemm<true, false, true, false, false><<<dim3(4, 256), 256, 0, stream>>>(
        Cb, wo_l, bo + l * 512, Ax, Bs, nullptr, 32768, 512, 512);
    k_decomp<<<256, 256, 0, stream>>>(Bs, Ax, Cb);  // x1 fp32 + bf16
    for (int ch = 0; ch < 4; ++ch) {
      const size_t eo = (size_t)ch * 8192 * 512;
      // y = relu(x1 @ c1^T) -> bf16
      k_gemm<false, true, false, true, false><<<dim3(16, 64), 256, 0, stream>>>(
          Cb + eo, c1_l, nullptr, nullptr, nullptr, Yb, 8192, 2048, 512);
      // t2 = y @ c2^T + x1
      k_gemm<false, false, true, false, false><<<dim3(4, 64), 256, 0, stream>>>(
          Yb, c2_l, nullptr, Ax + eo, Bs + eo, nullptr, 8192, 512, 2048);
    }
    k_decomp<<<256, 256, 0, stream>>>(Bs, Ax, Cb);  // next-layer x fp32 + bf16
  }

  k_lnstats<<<32768, 256, 0, stream>>>(Ax, muB, rsB);
  k_lastcat<<<128, 256, 0, stream>>>(Ax, muB, rsB, norm_w, cat);
  k_timecat<<<8, 256, 0, stream>>>(tvec, cat);
  // score = cat @ proj_w^T + proj_b   (K padded 536->544 with zeros)
  k_gemm<true, false, false, false, true><<<dim3(79, 1), 256, 0, stream>>>(
      cat, pwb, proj_b, nullptr, out, nullptr, 64, 10000, 544);
}

// Round 2
// 1420.154 us; speedup vs baseline: 1.2871x; 1.2871x over previous
//
#include <hip/hip_runtime.h>

// ---------------------------------------------------------------------------
// AppUsageFEDformer forward on MI355X (gfx950).
// Pipeline: embed -> 2x [Wq gemm -> DFT(32 modes) -> complex mix -> iDFT-GEMM ->
//           Wo gemm (+res) -> decomp -> conv1(relu) -> conv2(+res) -> decomp]
//           -> layernorm(+L-mean sub) -> last-token concat -> proj gemm.
// GEMMs: bf16 MFMA 16x16x32, 128x128x32 tiles, global_load_lds(16B) staging.
// R1->R2: k_inv (2x251us, VMEM-issue bound VALU kernel) replaced by a bf16
// MFMA GEMM: out[b*512+d][l] = sum_m coef[b,d,m]*Binv[l,m], K=64 packing
// Re(0..31),Im(0..31); Binv column 32 (Im_0) is 0 == numpy irfft drops Im0.
// Reference reshape quirk: fourier out (B,H,E,L) RESHAPED to (B,L,H*E) =>
// GEMM row index b*512+(h*64+o) already matches.
// ---------------------------------------------------------------------------

typedef unsigned short u16;
typedef float f32x4 __attribute__((ext_vector_type(4)));
typedef __bf16 bf16x8 __attribute__((ext_vector_type(8)));

__device__ __forceinline__ u16 f2b(float f) {
  unsigned u = __float_as_uint(f);
  return (u16)((u + 0x7FFFu + ((u >> 16) & 1u)) >> 16);
}

__device__ __forceinline__ void async16(const void* g, void* l) {
  __builtin_amdgcn_global_load_lds(
      (const __attribute__((address_space(1))) void*)g,
      (__attribute__((address_space(3))) void*)l, 16, 0, 0);
}

// ---------------- bf16 MFMA GEMM:  C = A(MxK) * B(NxK)^T (+bias)(+res)(relu)
template<bool BIAS, bool RELU, bool RES, bool OUTBF16, bool GUARD>
__global__ __launch_bounds__(256, 2)
void k_gemm(const u16* __restrict__ A, const u16* __restrict__ B,
            const float* __restrict__ bias, const float* __restrict__ res,
            float* __restrict__ Cf, u16* __restrict__ Cb,
            int M, int N, int K)
{
  __shared__ __align__(16) u16 sA[128 * 32];
  __shared__ __align__(16) u16 sB[128 * 32];
  const int tid = threadIdx.x;
  const int wave = tid >> 6, lane = tid & 63;
  const int bn = blockIdx.x, bm = blockIdx.y;
  const int wm = (wave >> 1) * 64, wn = (wave & 1) * 64;

  // staging geometry: 8 chunks of 1KB per 8KB tile; wave w owns chunks 2w,2w+1
  const int c0 = wave * 2, c1 = wave * 2 + 1;
  const int off0 = c0 * 1024 + lane * 16, off1 = c1 * 1024 + lane * 16;
  const int ra0 = off0 >> 6, ca0 = off0 & 63;   // row (64B per row of 32 bf16)
  const int ra1 = off1 >> 6, ca1 = off1 & 63;
  int gma0 = bm * 128 + ra0, gma1 = bm * 128 + ra1;
  int gnb0 = bn * 128 + ra0, gnb1 = bn * 128 + ra1;
  if (GUARD) {
    gma0 = gma0 < M ? gma0 : M - 1;
    gma1 = gma1 < M ? gma1 : M - 1;
    gnb0 = gnb0 < N ? gnb0 : N - 1;
    gnb1 = gnb1 < N ? gnb1 : N - 1;
  }
  const size_t rb = (size_t)K * 2;
  const char* pa0 = (const char*)A + (size_t)gma0 * rb + ca0;
  const char* pa1 = (const char*)A + (size_t)gma1 * rb + ca1;
  const char* pb0 = (const char*)B + (size_t)gnb0 * rb + ca0;
  const char* pb1 = (const char*)B + (size_t)gnb1 * rb + ca1;
  void* la0 = (void*)&sA[c0 * 512];
  void* la1 = (void*)&sA[c1 * 512];
  void* lb0 = (void*)&sB[c0 * 512];
  void* lb1 = (void*)&sB[c1 * 512];

  f32x4 acc[4][4];
  const f32x4 z = {0.f, 0.f, 0.f, 0.f};
#pragma unroll
  for (int i = 0; i < 4; ++i)
#pragma unroll
    for (int j = 0; j < 4; ++j) acc[i][j] = z;

  const int r = lane & 15, qd = lane >> 4;
  const int nk = K >> 5;
  for (int kt = 0; kt < nk; ++kt) {
    const size_t ko = (size_t)kt * 64;
    async16(pa0 + ko, la0);
    async16(pa1 + ko, la1);
    async16(pb0 + ko, lb0);
    async16(pb1 + ko, lb1);
    __syncthreads();   // drains vmcnt -> staged data visible
    bf16x8 af[4], bg[4];
#pragma unroll
    for (int mi = 0; mi < 4; ++mi)
      af[mi] = *(const bf16x8*)&sA[(wm + mi * 16 + r) * 32 + qd * 8];
#pragma unroll
    for (int ni = 0; ni < 4; ++ni)
      bg[ni] = *(const bf16x8*)&sB[(wn + ni * 16 + r) * 32 + qd * 8];
#pragma unroll
    for (int mi = 0; mi < 4; ++mi)
#pragma unroll
      for (int ni = 0; ni < 4; ++ni)
        acc[mi][ni] = __builtin_amdgcn_mfma_f32_16x16x32_bf16(
            af[mi], bg[ni], acc[mi][ni], 0, 0, 0);
    __syncthreads();   // all waves done reading LDS before next stage
  }

#pragma unroll
  for (int mi = 0; mi < 4; ++mi) {
#pragma unroll
    for (int ni = 0; ni < 4; ++ni) {
#pragma unroll
      for (int e = 0; e < 4; ++e) {
        int gm = bm * 128 + wm + mi * 16 + qd * 4 + e;  // C/D: row=quad*4+reg
        int gn = bn * 128 + wn + ni * 16 + r;           //       col=lane&15
        if (GUARD && (gm >= M || gn >= N)) continue;
        float v = acc[mi][ni][e];
        if (BIAS) v += bias[gn];
        if (RES)  v += res[(size_t)gm * N + gn];
        if (RELU) v = v > 0.f ? v : 0.f;
        if (OUTBF16) Cb[(size_t)gm * N + gn] = f2b(v);
        else         Cf[(size_t)gm * N + gn] = v;
      }
    }
  }
}

// ---------------- misc small kernels ----------------
// cosT/sinT [l][m] for the DFT; Binv [l][64] bf16 inverse-DFT B-operand:
//   m<32:  (m==0?1:2)/512 * cos(2pi m l/512)
//   m>=32: -(2/512) * sin(2pi (m-32) l/512)   (col 32 == 0 -> Im0 dropped)
__global__ void k_basis(float* __restrict__ cosT, float* __restrict__ sinT,
                        u16* __restrict__ Binv)
{
  int id = blockIdx.x * 256 + threadIdx.x;  // 512*64
  if (id >= 32768) return;
  int l = id >> 6, m = id & 63;
  int mm = m & 31;
  int ph = (l * mm) & 511;
  float ang = (float)ph * (6.283185307179586f / 512.f);
  float s, c;
  __sincosf(ang, &s, &c);
  if (m < 32) {
    cosT[l * 32 + m] = c;
    sinT[l * 32 + m] = s;
    float scale = (m == 0 ? 1.f : 2.f) * (1.f / 512.f);
    Binv[l * 64 + m] = f2b(scale * c);
  } else {
    Binv[l * 64 + m] = f2b(mm == 0 ? 0.f : (-2.f / 512.f) * s);
  }
}

__global__ void k_convert(const float* __restrict__ in, u16* __restrict__ out, int n)
{
  int id = blockIdx.x * 256 + threadIdx.x;
  if (id < n) out[id] = f2b(in[id]);
}

__global__ void k_convproj(const float* __restrict__ w, u16* __restrict__ o)
{
  int id = blockIdx.x * 256 + threadIdx.x;  // 10000*544
  if (id >= 10000 * 544) return;
  int n = id / 544, k = id % 544;
  o[id] = f2b(k < 536 ? w[(size_t)n * 536 + k] : 0.f);
}

__global__ void k_embed(const int* __restrict__ xapp, const float* __restrict__ xtime,
                        const float* __restrict__ emb, const float* __restrict__ tw,
                        const float* __restrict__ tb, float* __restrict__ xf,
                        u16* __restrict__ xb)
{
  int id = blockIdx.x * 256 + threadIdx.x;  // B*L*D = 16.7M
  int d = id & 511, bl = id >> 9;
  float v = emb[(size_t)xapp[bl] * 512 + d] + xtime[bl] * tw[d] + tb[d];
  xf[id] = v;
  xb[id] = f2b(v);
}

// DFT: spec[b][m][d]    = sum_l q[b,l,d] cos(2pi m l/512)   (m<32)
//      spec[b][32+m][d] = -sum_l q[b,l,d] sin(2pi m l/512)
__global__ __launch_bounds__(512)
void k_dft(const float* __restrict__ q, const float* __restrict__ cosT,
           const float* __restrict__ sinT, float* __restrict__ spec)
{
  __shared__ float bc[512][8];
  __shared__ float bs[512][8];
  int b = blockIdx.x, mg = blockIdx.y, t = threadIdx.x;
  for (int i = t; i < 4096; i += 512) {
    int l = i >> 3, mm = i & 7;
    bc[l][mm] = cosT[l * 32 + mg * 8 + mm];
    bs[l][mm] = sinT[l * 32 + mg * 8 + mm];
  }
  __syncthreads();
  float aR[8] = {}, aI[8] = {};
  const float* qb = q + (size_t)b * 262144;
#pragma unroll 4
  for (int l = 0; l < 512; ++l) {
    float v = qb[l * 512 + t];
#pragma unroll
    for (int mm = 0; mm < 8; ++mm) {
      aR[mm] = fmaf(v, bc[l][mm], aR[mm]);
      aI[mm] = fmaf(-v, bs[l][mm], aI[mm]);
    }
  }
  float* sp = spec + (size_t)b * 32768;
#pragma unroll
  for (int mm = 0; mm < 8; ++mm) {
    int m = mg * 8 + mm;
    sp[m * 512 + t] = aR[mm];
    sp[(32 + m) * 512 + t] = aI[mm];
  }
}

// mode mix: coef[b*512 + h*64+o][m] (Re), [32+m] (Im)  -- bf16 A-operand for
// the inverse-DFT GEMM.  out[b,h,o,m] = sum_i xs[b,h,i,m] * (wr+j wi)[h,i,o,m]
__global__ void k_mix(const float* __restrict__ spec, const float* __restrict__ wr,
                      const float* __restrict__ wi, u16* __restrict__ Ab)
{
  __shared__ float swr[64][64], swi[64][64];   // [i][o]
  __shared__ float sre[4][64], sim[4][64];     // [bsub][i]
  int h = blockIdx.x >> 5, m = blockIdx.x & 31, t = threadIdx.x;
  for (int i = t; i < 4096; i += 256) {
    int ii = i >> 6, oo = i & 63;
    size_t idx = ((size_t)((h * 64 + ii) * 64 + oo)) * 32 + m;
    swr[ii][oo] = wr[idx];
    swi[ii][oo] = wi[idx];
  }
  int o = t & 63, bsub = t >> 6;
  for (int b0 = 0; b0 < 64; b0 += 4) {
    __syncthreads();
    int b = b0 + bsub;
    const float* spb = spec + (size_t)b * 32768;
    sre[bsub][o] = spb[m * 512 + h * 64 + o];
    sim[bsub][o] = spb[(32 + m) * 512 + h * 64 + o];
    __syncthreads();
    float aR = 0.f, aI = 0.f;
#pragma unroll 8
    for (int i = 0; i < 64; ++i) {
      float xr = sre[bsub][i], xi = sim[bsub][i];
      float wrv = swr[i][o], wiv = swi[i][o];
      aR += xr * wrv - xi * wiv;
      aI += xr * wiv + xi * wrv;
    }
    size_t row = (size_t)b * 512 + h * 64 + o;
    Ab[row * 64 + m] = f2b(aR);
    Ab[row * 64 + 32 + m] = f2b(aI);
  }
}

// series_decomp: out = x - movavg_25(x) with edge padding; writes fp32 + bf16
__global__ void k_decomp(const float* __restrict__ in, float* __restrict__ outf,
                         u16* __restrict__ outb)
{
  int id = blockIdx.x * 256 + threadIdx.x;  // B*D*2 halves = 65536
  int d = id & 511;
  int half = (id >> 9) & 1;
  int b = id >> 10;
  const float* xb = in + (size_t)b * 262144 + d;
  int l0 = half * 256;
  float sum = 0.f;
#pragma unroll
  for (int j = -12; j <= 12; ++j) {
    int idx = l0 + j;
    idx = idx < 0 ? 0 : idx;
    sum += xb[idx * 512];
  }
#pragma unroll 4
  for (int l = l0; l < l0 + 256; ++l) {
    float xv = xb[l * 512];
    float o = xv - sum * (1.f / 25.f);
    size_t oi = ((size_t)b * 512 + l) * 512 + d;
    outf[oi] = o;
    outb[oi] = f2b(o);
    int ia = l + 13 > 511 ? 511 : l + 13;
    int ir = l - 12 < 0 ? 0 : l - 12;
    sum += xb[ia * 512] - xb[ir * 512];
  }
}

__global__ void k_lnstats(const float* __restrict__ x, float* __restrict__ mu,
                          float* __restrict__ rs)
{
  int row = blockIdx.x;
  const float* xr = x + (size_t)row * 512;
  int t = threadIdx.x;
  float v0 = xr[t], v1 = xr[t + 256];
  float s = v0 + v1, ss = v0 * v0 + v1 * v1;
#pragma unroll
  for (int off = 32; off; off >>= 1) {
    s += __shfl_down(s, off);
    ss += __shfl_down(ss, off);
  }
  __shared__ float as[4], ass[4];
  if ((t & 63) == 0) { as[t >> 6] = s; ass[t >> 6] = ss; }
  __syncthreads();
  if (t == 0) {
    float S = as[0] + as[1] + as[2] + as[3];
    float SS = ass[0] + ass[1] + ass[2] + ass[3];
    float m = S * (1.f / 512.f);
    float var = SS * (1.f / 512.f) - m * m;
    mu[row] = m;
    rs[row] = rsqrtf(var + 1e-5f);
  }
}

// head: cat[b][d] = w_d * (ln_last - mean_l(ln));  norm_b cancels.
__global__ void k_lastcat(const float* __restrict__ x, const float* __restrict__ mu,
                          const float* __restrict__ rs, const float* __restrict__ nw,
                          u16* __restrict__ cat)
{
  int id = blockIdx.x * 256 + threadIdx.x;  // B*D = 32768
  int b = id >> 9, d = id & 511;
  const float* xb = x + (size_t)b * 262144;
  const float* mub = mu + b * 512;
  const float* rsb = rs + b * 512;
  float acc = 0.f;
#pragma unroll 4
  for (int l = 0; l < 512; ++l)
    acc += (xb[l * 512 + d] - mub[l]) * rsb[l];
  float lastv = (xb[511 * 512 + d] - mub[511]) * rsb[511];
  float v = nw[d] * (lastv - acc * (1.f / 512.f));
  cat[b * 544 + d] = f2b(v);
}

__global__ void k_timecat(const float* __restrict__ tv, u16* __restrict__ cat)
{
  int id = blockIdx.x * 256 + threadIdx.x;  // 64*32
  if (id >= 2048) return;
  int b = id >> 5, j = id & 31;
  int pos = 512 + j;
  float v = (pos < 536) ? tv[((size_t)b * 512 + 511) * 24 + (pos - 512)] : 0.f;
  cat[b * 544 + pos] = f2b(v);
}

// ---------------------------------------------------------------------------
extern "C" void kernel_launch(void* const* d_in, const int* in_sizes, int n_in,
                              void* d_out, int out_size, void* d_ws, size_t ws_size,
                              hipStream_t stream)
{
  (void)in_sizes; (void)n_in; (void)out_size; (void)ws_size;
  const int*   x_app  = (const int*)  d_in[0];
  const float* x_time = (const float*)d_in[1];
  const float* tvec   = (const float*)d_in[2];
  // d_in[3] targets: unused by reference output
  const float* emb    = (const float*)d_in[4];
  const float* time_w = (const float*)d_in[5];
  const float* time_b = (const float*)d_in[6];
  const float* Wq     = (const float*)d_in[7];
  const float* bq     = (const float*)d_in[8];
  const float* Wo     = (const float*)d_in[9];
  const float* bo     = (const float*)d_in[10];
  const float* fwr    = (const float*)d_in[11];
  const float* fwi    = (const float*)d_in[12];
  const float* c1     = (const float*)d_in[13];
  const float* c2     = (const float*)d_in[14];
  const float* norm_w = (const float*)d_in[15];
  // d_in[16] norm_b: cancels in (xh - mean_l xh)
  const float* proj_w = (const float*)d_in[17];
  const float* proj_b = (const float*)d_in[18];
  float* out = (float*)d_out;

  char* w = (char*)d_ws;
  auto alloc = [&](size_t bytes) -> char* {
    char* p = w;
    w += (bytes + 255) & ~(size_t)255;
    return p;
  };
  float* Ax   = (float*)alloc(67108864);          // x fp32 (B,L,D)
  float* Bs   = (float*)alloc(67108864);          // q / t1 / t2 fp32
  u16*   Cb   = (u16*)  alloc(33554432);          // bf16 activation
  u16*   Yb   = (u16*)  alloc(33554432);          // conv1 out chunk (8192x2048)
  float* S1   = (float*)alloc(8388608);           // spec (B,64,D)
  u16*   Coef = (u16*)  alloc(4194304);           // mixed spectrum, GEMM-A bf16
  u16*   wqb  = (u16*)  alloc(2 * 262144 * 2);
  u16*   wob  = (u16*)  alloc(2 * 262144 * 2);
  u16*   c1b  = (u16*)  alloc(2 * 1048576 * 2);
  u16*   c2b  = (u16*)  alloc(2 * 1048576 * 2);
  u16*   pwb  = (u16*)  alloc(10000 * 544 * 2);
  float* cosT = (float*)alloc(65536);
  float* sinT = (float*)alloc(65536);
  u16*   Binv = (u16*)  alloc(512 * 64 * 2);
  float* muB  = (float*)alloc(131072);
  float* rsB  = (float*)alloc(131072);
  u16*   cat  = (u16*)  alloc(64 * 544 * 2);

  k_basis<<<128, 256, 0, stream>>>(cosT, sinT, Binv);
  k_convert<<<2048, 256, 0, stream>>>(Wq, wqb, 524288);
  k_convert<<<2048, 256, 0, stream>>>(Wo, wob, 524288);
  k_convert<<<8192, 256, 0, stream>>>(c1, c1b, 2097152);
  k_convert<<<8192, 256, 0, stream>>>(c2, c2b, 2097152);
  k_convproj<<<21250, 256, 0, stream>>>(proj_w, pwb);
  k_embed<<<65536, 256, 0, stream>>>(x_app, x_time, emb, time_w, time_b, Ax, Cb);

  for (int l = 0; l < 2; ++l) {
    const u16* wq_l = wqb + l * 262144;
    const u16* wo_l = wob + l * 262144;
    const u16* c1_l = c1b + l * 1048576;
    const u16* c2_l = c2b + l * 1048576;
    const float* fwr_l = fwr + (size_t)l * 1048576;
    const float* fwi_l = fwi + (size_t)l * 1048576;

    // q = x_bf16 @ Wq^T + bq
    k_gemm<true, false, false, false, false><<<dim3(4, 256), 256, 0, stream>>>(
        Cb, wq_l, bq + l * 512, nullptr, Bs, nullptr, 32768, 512, 512);
    k_dft<<<dim3(64, 4), 512, 0, stream>>>(Bs, cosT, sinT, S1);
    k_mix<<<256, 256, 0, stream>>>(S1, fwr_l, fwi_l, Coef);
    // inverse DFT as GEMM: Cb[b*512+d][l] = Coef @ Binv^T   (M=32768,N=512,K=64)
    k_gemm<false, false, false, true, false><<<dim3(4, 256), 256, 0, stream>>>(
        Coef, Binv, nullptr, nullptr, nullptr, Cb, 32768, 512, 64);
    // t1 = fourier_reshaped @ Wo^T + bo + x
    k_gemm<true, false, true, false, false><<<dim3(4, 256), 256, 0, stream>>>(
        Cb, wo_l, bo + l * 512, Ax, Bs, nullptr, 32768, 512, 512);
    k_decomp<<<256, 256, 0, stream>>>(Bs, Ax, Cb);  // x1 fp32 + bf16
    for (int ch = 0; ch < 4; ++ch) {
      const size_t eo = (size_t)ch * 8192 * 512;
      // y = relu(x1 @ c1^T) -> bf16
      k_gemm<false, true, false, true, false><<<dim3(16, 64), 256, 0, stream>>>(
          Cb + eo, c1_l, nullptr, nullptr, nullptr, Yb, 8192, 2048, 512);
      // t2 = y @ c2^T + x1
      k_gemm<false, false, true, false, false><<<dim3(4, 64), 256, 0, stream>>>(
          Yb, c2_l, nullptr, Ax + eo, Bs + eo, nullptr, 8192, 512, 2048);
    }
    k_decomp<<<256, 256, 0, stream>>>(Bs, Ax, Cb);  // next-layer x fp32 + bf16
  }

  k_lnstats<<<32768, 256, 0, stream>>>(Ax, muB, rsB);
  k_lastcat<<<128, 256, 0, stream>>>(Ax, muB, rsB, norm_w, cat);
  k_timecat<<<8, 256, 0, stream>>>(tvec, cat);
  // score = cat @ proj_w^T + proj_b   (K padded 536->544 with zeros)
  k_gemm<true, false, false, false, true><<<dim3(79, 1), 256, 0, stream>>>(
      cat, pwb, proj_b, nullptr, out, nullptr, 64, 10000, 544);
}

// Round 4
// 1328.675 us; speedup vs baseline: 1.3757x; 1.0688x over previous
//
#include <hip/hip_runtime.h>

// ---------------------------------------------------------------------------
// AppUsageFEDformer forward on MI355X (gfx950).
// embed -> 2x [Wq gemm(->qT bf16) -> DFT-GEMM -> mix -> iDFT-GEMM ->
//              Wo gemm(+res) -> decomp -> conv1(relu) -> conv2(+res) -> decomp]
//          -> layernorm(+L-mean sub) -> last-token concat -> proj gemm.
// R3->R4: fix workspace overflow (R3 = 256.8 MiB > 256 MiB ws): qTb aliased
// onto Yb (disjoint live ranges: qT dies at spec-GEMM, Yb lives only in the
// conv chunk loop).  Total now 235.7 MB.  GEMM core unchanged from R3:
// XOR-swizzled LDS staging, double-buffered one-barrier K-loop, DFT/iDFT as
// bf16 MFMA GEMMs.  spec layout [b][m:Re,32+m:Im][d] preserved for k_mix.
// ---------------------------------------------------------------------------

typedef unsigned short u16;
typedef float f32x4 __attribute__((ext_vector_type(4)));
typedef __bf16 bf16x8 __attribute__((ext_vector_type(8)));

__device__ __forceinline__ u16 f2b(float f) {
  unsigned u = __float_as_uint(f);
  return (u16)((u + 0x7FFFu + ((u >> 16) & 1u)) >> 16);
}

__device__ __forceinline__ void async16(const void* g, void* l) {
  __builtin_amdgcn_global_load_lds(
      (const __attribute__((address_space(1))) void*)g,
      (__attribute__((address_space(3))) void*)l, 16, 0, 0);
}

// ---------------- bf16 MFMA GEMM:  C = A(MxK) * B(NxK)^T (+bias)(+res)(relu)
// Optional batch (blockIdx.z strides, elements) and transposed store
// (C[gn*M + gm], used for qT and spec).  LDS XOR swizzle: physical group
// p holds global group g = p ^ ((row>>1)&3); fragment read uses
// p = qd ^ ((lane>>1)&3)  -> 2-way bank aliasing max (free).
template<bool BIAS, bool RELU, bool RES, bool OUTBF16, bool GUARD, bool TRANS>
__global__ __launch_bounds__(256, 2)
void k_gemm(const u16* __restrict__ A, const u16* __restrict__ B,
            const float* __restrict__ bias, const float* __restrict__ res,
            float* __restrict__ Cf, u16* __restrict__ Cb,
            int M, int N, int K,
            long zA, long zB, long zC)
{
  __shared__ __align__(16) u16 sA[2][128 * 32];
  __shared__ __align__(16) u16 sB[2][128 * 32];
  const int tid = threadIdx.x;
  const int wave = tid >> 6, lane = tid & 63;
  const int bn = blockIdx.x, bm = blockIdx.y, bz = blockIdx.z;
  const int wm = (wave >> 1) * 64, wn = (wave & 1) * 64;

  A += (size_t)bz * zA;
  B += (size_t)bz * zB;

  // staging: wave w owns 1KB chunks 2w,2w+1 of each tile; lane covers
  // (row rowc=lane>>2 within chunk, physical group p=lane&3); it must FETCH
  // logical group g = p ^ s(rowc), s(row)=(row>>1)&3.
  const int c0 = wave * 2, c1 = wave * 2 + 1;
  const int rowc = lane >> 2;
  const int g = (lane & 3) ^ ((lane >> 3) & 3);
  const int rA0 = c0 * 16 + rowc, rA1 = c1 * 16 + rowc;
  int gma0 = bm * 128 + rA0, gma1 = bm * 128 + rA1;
  int gnb0 = bn * 128 + rA0, gnb1 = bn * 128 + rA1;
  if (GUARD) {
    gma0 = gma0 < M ? gma0 : M - 1;
    gma1 = gma1 < M ? gma1 : M - 1;
    gnb0 = gnb0 < N ? gnb0 : N - 1;
    gnb1 = gnb1 < N ? gnb1 : N - 1;
  }
  const size_t rb = (size_t)K * 2;
  const char* pa0 = (const char*)A + (size_t)gma0 * rb + g * 16;
  const char* pa1 = (const char*)A + (size_t)gma1 * rb + g * 16;
  const char* pb0 = (const char*)B + (size_t)gnb0 * rb + g * 16;
  const char* pb1 = (const char*)B + (size_t)gnb1 * rb + g * 16;

  f32x4 acc[4][4];
  const f32x4 z = {0.f, 0.f, 0.f, 0.f};
#pragma unroll
  for (int i = 0; i < 4; ++i)
#pragma unroll
    for (int j = 0; j < 4; ++j) acc[i][j] = z;

  const int r = lane & 15, qd = lane >> 4;
  const int sw = (lane >> 1) & 3;         // fragment-read swizzle term
  const int pA = (qd ^ sw) * 8;           // physical 8-elem group offset
  const int nk = K >> 5;

  auto stage = [&](int kt, int pg) {
    const size_t ko = (size_t)kt * 64;
    async16(pa0 + ko, (void*)&sA[pg][c0 * 512]);
    async16(pa1 + ko, (void*)&sA[pg][c1 * 512]);
    async16(pb0 + ko, (void*)&sB[pg][c0 * 512]);
    async16(pb1 + ko, (void*)&sB[pg][c1 * 512]);
  };

  stage(0, 0);
  int pg = 0;
  for (int kt = 0; kt < nk; ++kt) {
    __syncthreads();                 // drains async stage of tile kt
    if (kt + 1 < nk) stage(kt + 1, pg ^ 1);   // prefetch flies during MFMA
    bf16x8 af[4], bg[4];
#pragma unroll
    for (int mi = 0; mi < 4; ++mi)
      af[mi] = *(const bf16x8*)&sA[pg][(wm + mi * 16 + r) * 32 + pA];
#pragma unroll
    for (int ni = 0; ni < 4; ++ni)
      bg[ni] = *(const bf16x8*)&sB[pg][(wn + ni * 16 + r) * 32 + pA];
#pragma unroll
    for (int mi = 0; mi < 4; ++mi)
#pragma unroll
      for (int ni = 0; ni < 4; ++ni)
        acc[mi][ni] = __builtin_amdgcn_mfma_f32_16x16x32_bf16(
            af[mi], bg[ni], acc[mi][ni], 0, 0, 0);
    pg ^= 1;
  }

  if (Cf) Cf += (size_t)bz * zC;
  if (Cb) Cb += (size_t)bz * zC;
#pragma unroll
  for (int mi = 0; mi < 4; ++mi) {
#pragma unroll
    for (int ni = 0; ni < 4; ++ni) {
#pragma unroll
      for (int e = 0; e < 4; ++e) {
        int gm = bm * 128 + wm + mi * 16 + qd * 4 + e;  // C/D: row=quad*4+reg
        int gn = bn * 128 + wn + ni * 16 + r;           //       col=lane&15
        if (GUARD && (gm >= M || gn >= N)) continue;
        float v = acc[mi][ni][e];
        if (BIAS) v += bias[gn];
        if (RES)  v += res[(size_t)gm * N + gn];
        if (RELU) v = v > 0.f ? v : 0.f;
        size_t oi = TRANS ? ((size_t)gn * M + gm) : ((size_t)gm * N + gn);
        if (OUTBF16) Cb[oi] = f2b(v);
        else         Cf[oi] = v;
      }
    }
  }
}

// ---------------- misc small kernels ----------------
// dftB [64][512] bf16 B-operand: row m<32 = cos(2pi m l/512); row 32+m =
// -sin(2pi m l/512)  (=> C = Re / Im of rfft).
// Binv [l][64] bf16 inverse-DFT B-operand:
//   m<32:  (m==0?1:2)/512 * cos(2pi m l/512)
//   m>=32: -(2/512) * sin(2pi (m-32) l/512)   (col 32 == 0 -> Im0 dropped)
__global__ void k_basis(u16* __restrict__ dftB, u16* __restrict__ Binv)
{
  int id = blockIdx.x * 256 + threadIdx.x;  // 32768
  if (id >= 32768) return;
  {
    int m = id >> 9, l = id & 511;
    int mm = m & 31;
    float ang = (float)((l * mm) & 511) * (6.283185307179586f / 512.f);
    float s, c;
    __sincosf(ang, &s, &c);
    dftB[id] = f2b(m < 32 ? c : -s);
  }
  {
    int l = id >> 6, m = id & 63;
    int mm = m & 31;
    float ang = (float)((l * mm) & 511) * (6.283185307179586f / 512.f);
    float s, c;
    __sincosf(ang, &s, &c);
    float v;
    if (m < 32) v = (m == 0 ? 1.f : 2.f) * (1.f / 512.f) * c;
    else        v = (mm == 0 ? 0.f : (-2.f / 512.f) * s);
    Binv[id] = f2b(v);
  }
}

__global__ void k_convert(const float* __restrict__ in, u16* __restrict__ out, int n)
{
  int id = blockIdx.x * 256 + threadIdx.x;
  if (id < n) out[id] = f2b(in[id]);
}

__global__ void k_convproj(const float* __restrict__ w, u16* __restrict__ o)
{
  int id = blockIdx.x * 256 + threadIdx.x;  // 10000*544
  if (id >= 10000 * 544) return;
  int n = id / 544, k = id % 544;
  o[id] = f2b(k < 536 ? w[(size_t)n * 536 + k] : 0.f);
}

__global__ void k_embed(const int* __restrict__ xapp, const float* __restrict__ xtime,
                        const float* __restrict__ emb, const float* __restrict__ tw,
                        const float* __restrict__ tb, float* __restrict__ xf,
                        u16* __restrict__ xb)
{
  int id = blockIdx.x * 256 + threadIdx.x;  // B*L*D = 16.7M
  int d = id & 511, bl = id >> 9;
  float v = emb[(size_t)xapp[bl] * 512 + d] + xtime[bl] * tw[d] + tb[d];
  xf[id] = v;
  xb[id] = f2b(v);
}

// mode mix: coef[b*512 + h*64+o][m] (Re), [32+m] (Im)  -- bf16 A-operand for
// the inverse-DFT GEMM.  out[b,h,o,m] = sum_i xs[b,h,i,m] * (wr+j wi)[h,i,o,m]
__global__ void k_mix(const float* __restrict__ spec, const float* __restrict__ wr,
                      const float* __restrict__ wi, u16* __restrict__ Ab)
{
  __shared__ float swr[64][64], swi[64][64];   // [i][o]
  __shared__ float sre[4][64], sim[4][64];     // [bsub][i]
  int h = blockIdx.x >> 5, m = blockIdx.x & 31, t = threadIdx.x;
  for (int i = t; i < 4096; i += 256) {
    int ii = i >> 6, oo = i & 63;
    size_t idx = ((size_t)((h * 64 + ii) * 64 + oo)) * 32 + m;
    swr[ii][oo] = wr[idx];
    swi[ii][oo] = wi[idx];
  }
  int o = t & 63, bsub = t >> 6;
  for (int b0 = 0; b0 < 64; b0 += 4) {
    __syncthreads();
    int b = b0 + bsub;
    const float* spb = spec + (size_t)b * 32768;
    sre[bsub][o] = spb[m * 512 + h * 64 + o];
    sim[bsub][o] = spb[(32 + m) * 512 + h * 64 + o];
    __syncthreads();
    float aR = 0.f, aI = 0.f;
#pragma unroll 8
    for (int i = 0; i < 64; ++i) {
      float xr = sre[bsub][i], xi = sim[bsub][i];
      float wrv = swr[i][o], wiv = swi[i][o];
      aR += xr * wrv - xi * wiv;
      aI += xr * wiv + xi * wrv;
    }
    size_t row = (size_t)b * 512 + h * 64 + o;
    Ab[row * 64 + m] = f2b(aR);
    Ab[row * 64 + 32 + m] = f2b(aI);
  }
}

// series_decomp: out = x - movavg_25(x) with edge padding; writes fp32 + bf16
__global__ void k_decomp(const float* __restrict__ in, float* __restrict__ outf,
                         u16* __restrict__ outb)
{
  int id = blockIdx.x * 256 + threadIdx.x;  // B*D*2 halves = 65536
  int d = id & 511;
  int half = (id >> 9) & 1;
  int b = id >> 10;
  const float* xb = in + (size_t)b * 262144 + d;
  int l0 = half * 256;
  float sum = 0.f;
#pragma unroll
  for (int j = -12; j <= 12; ++j) {
    int idx = l0 + j;
    idx = idx < 0 ? 0 : idx;
    sum += xb[idx * 512];
  }
#pragma unroll 4
  for (int l = l0; l < l0 + 256; ++l) {
    float xv = xb[l * 512];
    float o = xv - sum * (1.f / 25.f);
    size_t oi = ((size_t)b * 512 + l) * 512 + d;
    outf[oi] = o;
    outb[oi] = f2b(o);
    int ia = l + 13 > 511 ? 511 : l + 13;
    int ir = l - 12 < 0 ? 0 : l - 12;
    sum += xb[ia * 512] - xb[ir * 512];
  }
}

__global__ void k_lnstats(const float* __restrict__ x, float* __restrict__ mu,
                          float* __restrict__ rs)
{
  int row = blockIdx.x;
  const float* xr = x + (size_t)row * 512;
  int t = threadIdx.x;
  float v0 = xr[t], v1 = xr[t + 256];
  float s = v0 + v1, ss = v0 * v0 + v1 * v1;
#pragma unroll
  for (int off = 32; off; off >>= 1) {
    s += __shfl_down(s, off);
    ss += __shfl_down(ss, off);
  }
  __shared__ float as[4], ass[4];
  if ((t & 63) == 0) { as[t >> 6] = s; ass[t >> 6] = ss; }
  __syncthreads();
  if (t == 0) {
    float S = as[0] + as[1] + as[2] + as[3];
    float SS = ass[0] + ass[1] + ass[2] + ass[3];
    float m = S * (1.f / 512.f);
    float var = SS * (1.f / 512.f) - m * m;
    mu[row] = m;
    rs[row] = rsqrtf(var + 1e-5f);
  }
}

// head: cat[b][d] = w_d * (ln_last - mean_l(ln));  norm_b cancels.
__global__ void k_lastcat(const float* __restrict__ x, const float* __restrict__ mu,
                          const float* __restrict__ rs, const float* __restrict__ nw,
                          u16* __restrict__ cat)
{
  int id = blockIdx.x * 256 + threadIdx.x;  // B*D = 32768
  int b = id >> 9, d = id & 511;
  const float* xb = x + (size_t)b * 262144;
  const float* mub = mu + b * 512;
  const float* rsb = rs + b * 512;
  float acc = 0.f;
#pragma unroll 4
  for (int l = 0; l < 512; ++l)
    acc += (xb[l * 512 + d] - mub[l]) * rsb[l];
  float lastv = (xb[511 * 512 + d] - mub[511]) * rsb[511];
  float v = nw[d] * (lastv - acc * (1.f / 512.f));
  cat[b * 544 + d] = f2b(v);
}

__global__ void k_timecat(const float* __restrict__ tv, u16* __restrict__ cat)
{
  int id = blockIdx.x * 256 + threadIdx.x;  // 64*32
  if (id >= 2048) return;
  int b = id >> 5, j = id & 31;
  int pos = 512 + j;
  float v = (pos < 536) ? tv[((size_t)b * 512 + 511) * 24 + (pos - 512)] : 0.f;
  cat[b * 544 + pos] = f2b(v);
}

// ---------------------------------------------------------------------------
extern "C" void kernel_launch(void* const* d_in, const int* in_sizes, int n_in,
                              void* d_out, int out_size, void* d_ws, size_t ws_size,
                              hipStream_t stream)
{
  (void)in_sizes; (void)n_in; (void)out_size; (void)ws_size;
  const int*   x_app  = (const int*)  d_in[0];
  const float* x_time = (const float*)d_in[1];
  const float* tvec   = (const float*)d_in[2];
  // d_in[3] targets: unused by reference output
  const float* emb    = (const float*)d_in[4];
  const float* time_w = (const float*)d_in[5];
  const float* time_b = (const float*)d_in[6];
  const float* Wq     = (const float*)d_in[7];
  const float* bq     = (const float*)d_in[8];
  const float* Wo     = (const float*)d_in[9];
  const float* bo     = (const float*)d_in[10];
  const float* fwr    = (const float*)d_in[11];
  const float* fwi    = (const float*)d_in[12];
  const float* c1     = (const float*)d_in[13];
  const float* c2     = (const float*)d_in[14];
  const float* norm_w = (const float*)d_in[15];
  // d_in[16] norm_b: cancels in (xh - mean_l xh)
  const float* proj_w = (const float*)d_in[17];
  const float* proj_b = (const float*)d_in[18];
  float* out = (float*)d_out;

  char* w = (char*)d_ws;
  auto alloc = [&](size_t bytes) -> char* {
    char* p = w;
    w += (bytes + 255) & ~(size_t)255;
    return p;
  };
  // Workspace budget: 235.7 MB total (R3's extra 32MB buffer overflowed 256MiB)
  float* Ax   = (float*)alloc(67108864);          // x fp32 (B,L,D)
  float* Bs   = (float*)alloc(67108864);          // t1/t2 fp32
  u16*   Cb   = (u16*)  alloc(33554432);          // bf16 activation
  u16*   YqT  = (u16*)  alloc(33554432);          // qT bf16 (early) / conv1 out (late)
  float* S1   = (float*)alloc(8388608);           // spec (B,64,D) fp32
  u16*   Coef = (u16*)  alloc(4194304);           // mixed spectrum, GEMM-A bf16
  u16*   wqb  = (u16*)  alloc(2 * 262144 * 2);
  u16*   wob  = (u16*)  alloc(2 * 262144 * 2);
  u16*   c1b  = (u16*)  alloc(2 * 1048576 * 2);
  u16*   c2b  = (u16*)  alloc(2 * 1048576 * 2);
  u16*   pwb  = (u16*)  alloc(10000 * 544 * 2);
  u16*   dftB = (u16*)  alloc(64 * 512 * 2);
  u16*   Binv = (u16*)  alloc(512 * 64 * 2);
  float* muB  = (float*)alloc(131072);
  float* rsB  = (float*)alloc(131072);
  u16*   cat  = (u16*)  alloc(64 * 544 * 2);

  k_basis<<<128, 256, 0, stream>>>(dftB, Binv);
  k_convert<<<2048, 256, 0, stream>>>(Wq, wqb, 524288);
  k_convert<<<2048, 256, 0, stream>>>(Wo, wob, 524288);
  k_convert<<<8192, 256, 0, stream>>>(c1, c1b, 2097152);
  k_convert<<<8192, 256, 0, stream>>>(c2, c2b, 2097152);
  k_convproj<<<21250, 256, 0, stream>>>(proj_w, pwb);
  k_embed<<<65536, 256, 0, stream>>>(x_app, x_time, emb, time_w, time_b, Ax, Cb);

  for (int l = 0; l < 2; ++l) {
    const u16* wq_l = wqb + l * 262144;
    const u16* wo_l = wob + l * 262144;
    const u16* c1_l = c1b + l * 1048576;
    const u16* c2_l = c2b + l * 1048576;
    const float* fwr_l = fwr + (size_t)l * 1048576;
    const float* fwi_l = fwi + (size_t)l * 1048576;

    // qT[b][d][l] = (x @ Wq^T + bq)^T, bf16, batched over b, TRANS store
    k_gemm<true, false, false, true, false, true>
        <<<dim3(4, 4, 64), 256, 0, stream>>>(
        Cb, wq_l, bq + l * 512, nullptr, nullptr, YqT, 512, 512, 512,
        262144, 0, 262144);
    // spec[b][m][d] = qT[b] @ dftB^T  (M=512,N=64 pad 128,K=512), TRANS store
    k_gemm<false, false, false, false, true, true>
        <<<dim3(1, 4, 64), 256, 0, stream>>>(
        YqT, dftB, nullptr, nullptr, S1, nullptr, 512, 64, 512,
        262144, 0, 32768);
    k_mix<<<256, 256, 0, stream>>>(S1, fwr_l, fwi_l, Coef);
    // inverse DFT as GEMM: Cb[b*512+d][l] = Coef @ Binv^T  (M=32768,N=512,K=64)
    k_gemm<false, false, false, true, false, false>
        <<<dim3(4, 256, 1), 256, 0, stream>>>(
        Coef, Binv, nullptr, nullptr, nullptr, Cb, 32768, 512, 64, 0, 0, 0);
    // t1 = fourier_reshaped @ Wo^T + bo + x
    k_gemm<true, false, true, false, false, false>
        <<<dim3(4, 256, 1), 256, 0, stream>>>(
        Cb, wo_l, bo + l * 512, Ax, Bs, nullptr, 32768, 512, 512, 0, 0, 0);
    k_decomp<<<256, 256, 0, stream>>>(Bs, Ax, Cb);  // x1 fp32 + bf16
    for (int ch = 0; ch < 4; ++ch) {
      const size_t eo = (size_t)ch * 8192 * 512;
      // y = relu(x1 @ c1^T) -> bf16
      k_gemm<false, true, false, true, false, false>
          <<<dim3(16, 64, 1), 256, 0, stream>>>(
          Cb + eo, c1_l, nullptr, nullptr, nullptr, YqT, 8192, 2048, 512,
          0, 0, 0);
      // t2 = y @ c2^T + x1
      k_gemm<false, false, true, false, false, false>
          <<<dim3(4, 64, 1), 256, 0, stream>>>(
          YqT, c2_l, nullptr, Ax + eo, Bs + eo, nullptr, 8192, 512, 2048,
          0, 0, 0);
    }
    k_decomp<<<256, 256, 0, stream>>>(Bs, Ax, Cb);  // next-layer x fp32 + bf16
  }

  k_lnstats<<<32768, 256, 0, stream>>>(Ax, muB, rsB);
  k_lastcat<<<128, 256, 0, stream>>>(Ax, muB, rsB, norm_w, cat);
  k_timecat<<<8, 256, 0, stream>>>(tvec, cat);
  // score = cat @ proj_w^T + proj_b   (K padded 536->544 with zeros)
  k_gemm<true, false, false, false, true, false>
      <<<dim3(79, 1, 1), 256, 0, stream>>>(
      cat, pwb, proj_b, nullptr, out, nullptr, 64, 10000, 544, 0, 0, 0);
}